// Round 1
// baseline (191.497 us; speedup 1.0000x reference)
//
#include <hip/hip_runtime.h>
#include <hip/hip_bf16.h>

#define LOG2E    1.4426950408889634f
#define TWOLOG2E 2.8853900817779268f

// tanh(x) = 1 - 2/(1+e^{2x});  e^{2x} = 2^(x*2*log2(e))
// Large +x: exp2 -> inf, rcp -> 0, result 1.  Large -x: exp2 -> 0, result -1.
__device__ __forceinline__ float tanh_fast(float x) {
    float e = __builtin_amdgcn_exp2f(x * TWOLOG2E);
    return 1.0f - 2.0f * __builtin_amdgcn_rcpf(1.0f + e);
}

// C[m,n] = sum_h A[m*lda+h] * W[n*ldw+h]  (+ bias[n])   -- "NT" gemm, f32
// block: 256 threads, tile 64x64, K-chunk 16
__global__ __launch_bounds__(256) void gemm_nt_f32(
    const float* __restrict__ A, const float* __restrict__ W,
    const float* __restrict__ bias, float* __restrict__ C,
    int lda, int ldw, int ldc, int K)
{
    // LDS stored transposed: As[k][m], Ws[k][n]; row stride 68 floats:
    // 272B = 16B-aligned rows, bank = (4*c + r) % 32 -> worst 2-way (free).
    __shared__ __align__(16) float As[16][68];
    __shared__ __align__(16) float Ws[16][68];
    const int t    = threadIdx.x;
    const int m0   = blockIdx.y * 64;
    const int n0   = blockIdx.x * 64;
    const int rowL = t >> 2;          // 0..63 : which m (or n) row this thread stages
    const int colL = (t & 3) << 2;    // 0,4,8,12 : which k-subchunk (float4)
    const float* Ap = A + (size_t)(m0 + rowL) * lda;
    const float* Wp = W + (size_t)(n0 + rowL) * ldw;
    const int tx = t & 15;            // -> m micro-tile
    const int ty = t >> 4;            // -> n micro-tile
    float acc[4][4] = {};

    for (int k0 = 0; k0 < K; k0 += 16) {
        float4 av = *(const float4*)(Ap + k0 + colL);
        float4 wv = *(const float4*)(Wp + k0 + colL);
        As[colL + 0][rowL] = av.x; As[colL + 1][rowL] = av.y;
        As[colL + 2][rowL] = av.z; As[colL + 3][rowL] = av.w;
        Ws[colL + 0][rowL] = wv.x; Ws[colL + 1][rowL] = wv.y;
        Ws[colL + 2][rowL] = wv.z; Ws[colL + 3][rowL] = wv.w;
        __syncthreads();
        #pragma unroll
        for (int kk = 0; kk < 16; ++kk) {
            float4 a4 = *(const float4*)&As[kk][tx << 2];
            float4 w4 = *(const float4*)&Ws[kk][ty << 2];
            float am[4] = {a4.x, a4.y, a4.z, a4.w};
            float wm[4] = {w4.x, w4.y, w4.z, w4.w};
            #pragma unroll
            for (int i = 0; i < 4; ++i)
                #pragma unroll
                for (int j = 0; j < 4; ++j)
                    acc[i][j] = fmaf(am[i], wm[j], acc[i][j]);
        }
        __syncthreads();
    }

    float bv[4] = {0.f, 0.f, 0.f, 0.f};
    if (bias) {
        #pragma unroll
        for (int j = 0; j < 4; ++j) bv[j] = bias[n0 + (ty << 2) + j];
    }
    #pragma unroll
    for (int i = 0; i < 4; ++i) {
        float4 o;
        o.x = acc[i][0] + bv[0];
        o.y = acc[i][1] + bv[1];
        o.z = acc[i][2] + bv[2];
        o.w = acc[i][3] + bv[3];
        *(float4*)(C + (size_t)(m0 + (tx << 2) + i) * ldc + n0 + (ty << 2)) = o;
    }
}

// x[b,q,l] = sum_k tanh(bp[b,l,k] + qpb[b,q,k]) * v_w[k]  + v_b
// block: 256 threads = 16 q x 16 l tile; grid (l_tiles=32, q_tiles=4, b=4)
__global__ __launch_bounds__(256) void attn_scores(
    const float* __restrict__ bp, const float* __restrict__ qpb,
    const float* __restrict__ v_w, const float* __restrict__ v_b,
    float* __restrict__ X)
{
    __shared__ __align__(16) float bpL[16][68];
    __shared__ __align__(16) float qpL[16][68];
    __shared__ __align__(16) float vwL[64];
    const int t   = threadIdx.x;
    const int b   = blockIdx.z;
    const int q0  = blockIdx.y * 16;
    const int l0  = blockIdx.x * 16;
    const int li  = t & 15;
    const int qi  = t >> 4;
    const int row = t >> 4;           // staging row 0..15
    const int col = (t & 15) << 2;    // staging col (float4) 0..60
    const float* bprow = bp  + (size_t)(b * 512 + l0 + row) * 768;
    const float* qprow = qpb + (size_t)(b * 64  + q0 + row) * 768;
    float acc = 0.f;

    for (int k0 = 0; k0 < 768; k0 += 64) {
        *(float4*)&bpL[row][col] = *(const float4*)(bprow + k0 + col);
        *(float4*)&qpL[row][col] = *(const float4*)(qprow + k0 + col);
        if (t < 16) *(float4*)&vwL[t << 2] = *(const float4*)(v_w + k0 + (t << 2));
        __syncthreads();
        #pragma unroll
        for (int kk = 0; kk < 64; kk += 4) {
            float4 b4 = *(const float4*)&bpL[li][kk];
            float4 q4 = *(const float4*)&qpL[qi][kk];
            float4 v4 = *(const float4*)&vwL[kk];
            acc = fmaf(tanh_fast(b4.x + q4.x), v4.x, acc);
            acc = fmaf(tanh_fast(b4.y + q4.y), v4.y, acc);
            acc = fmaf(tanh_fast(b4.z + q4.z), v4.z, acc);
            acc = fmaf(tanh_fast(b4.w + q4.w), v4.w, acc);
        }
        __syncthreads();
    }
    X[(size_t)(b * 64 + q0 + qi) * 512 + l0 + li] = acc + v_b[0];
}

// masked softmax over l (512) per (b,q) row; mask: int32 0/1 per harness int convention
__global__ __launch_bounds__(512) void softmax_mask(
    const float* __restrict__ X, const int* __restrict__ mask,
    float* __restrict__ out)
{
    const int bq  = blockIdx.x;       // b*64 + q
    const int b   = bq >> 6;
    const int l   = threadIdx.x;      // 0..511
    const int wid = l >> 6;
    __shared__ float red[8];

    float v = X[(size_t)bq * 512 + l];
    const bool mk = (mask[b * 512 + l] != 0);
    v = mk ? v : -1e25f;

    float m = v;
    #pragma unroll
    for (int o = 32; o; o >>= 1) m = fmaxf(m, __shfl_xor(m, o));
    if ((l & 63) == 0) red[wid] = m;
    __syncthreads();
    #pragma unroll
    for (int i = 0; i < 8; ++i) m = fmaxf(m, red[i]);

    float e = __builtin_amdgcn_exp2f((v - m) * LOG2E);  // masked -> exp2(-huge) = 0
    float s = e;
    #pragma unroll
    for (int o = 32; o; o >>= 1) s += __shfl_xor(s, o);
    __syncthreads();                  // red reuse
    if ((l & 63) == 0) red[wid] = s;
    __syncthreads();
    s = 0.f;
    #pragma unroll
    for (int i = 0; i < 8; ++i) s += red[i];

    out[(size_t)bq * 512 + l] = e / s;
}

extern "C" void kernel_launch(void* const* d_in, const int* in_sizes, int n_in,
                              void* d_out, int out_size, void* d_ws, size_t ws_size,
                              hipStream_t stream)
{
    const float* bert  = (const float*)d_in[0];   // (4,512,768) f32
    const float* query = (const float*)d_in[1];   // (4,64,768)  f32
    const int*   mask  = (const int*)  d_in[2];   // (4,512)     int32 (bool)
    const float* W_w   = (const float*)d_in[3];   // (768,1536)  f32
    const float* W_b   = (const float*)d_in[4];   // (768,)      f32
    const float* v_w   = (const float*)d_in[5];   // (1,768)     f32
    const float* v_b   = (const float*)d_in[6];   // (1,)        f32

    float* bp  = (float*)d_ws;              // 2048*768 f32 = 6.0 MB
    float* qpb = bp  + (size_t)2048 * 768;  //  256*768 f32 = 0.75 MB
    float* X   = qpb + (size_t)256  * 768;  //  256*512 f32 = 0.5 MB
    float* out = (float*)d_out;             // (4,64,512) f32

    // bp[b*512+l, k] = bert . W_bert^T      (W_bert = W_w[:, :768], row k at k*1536)
    gemm_nt_f32<<<dim3(12, 32), 256, 0, stream>>>(bert, W_w, nullptr, bp, 768, 1536, 768, 768);
    // qpb[b*64+q, k] = query . W_query^T + W_b   (W_query = W_w[:, 768:])
    gemm_nt_f32<<<dim3(12, 4), 256, 0, stream>>>(query, W_w + 768, W_b, qpb, 768, 1536, 768, 768);
    // x = sum_k tanh(bp + qpb) * v_w + v_b
    attn_scores<<<dim3(32, 4, 4), 256, 0, stream>>>(bp, qpb, v_w, v_b, X);
    // masked softmax over l
    softmax_mask<<<dim3(256), 512, 0, stream>>>(X, mask, out);
}

// Round 2
// 148.341 us; speedup vs baseline: 1.2909x; 1.2909x over previous
//
#include <hip/hip_runtime.h>
#include <hip/hip_bf16.h>

#define LOG2E    1.4426950408889634f
#define TWOLOG2E 2.8853900817779268f

typedef short bf16x8 __attribute__((ext_vector_type(8)));
typedef float f32x4  __attribute__((ext_vector_type(4)));

static __device__ __forceinline__ float bf16_to_f(unsigned short u) {
    union { unsigned int i; float f; } v; v.i = ((unsigned int)u) << 16; return v.f;
}
static __device__ __forceinline__ unsigned short f_to_bf16_rne(float x) {
    union { float f; unsigned int i; } v; v.f = x;
    unsigned int lsb = (v.i >> 16) & 1u;
    v.i += 0x7fffu + lsb;
    return (unsigned short)(v.i >> 16);
}

// tanh(x) = 1 - 2/(1+e^{2x})
__device__ __forceinline__ float tanh_fast(float x) {
    float e = __builtin_amdgcn_exp2f(x * TWOLOG2E);
    return 1.0f - 2.0f * __builtin_amdgcn_rcpf(1.0f + e);
}

// ---- split f32 -> bf16 hi + bf16 lo, over [bert | query] -> Acat and W_w -> Wcat ----
// float4 counts: bert 393216, query 49152 (A total 442368), W 294912. total 737280.
__global__ __launch_bounds__(256) void cast_split_all(
    const float* __restrict__ bert, const float* __restrict__ query,
    const float* __restrict__ Ww,
    unsigned short* __restrict__ Ahi, unsigned short* __restrict__ Alo,
    unsigned short* __restrict__ Whi, unsigned short* __restrict__ Wlo)
{
    const int i = blockIdx.x * 256 + threadIdx.x;   // grid sized exactly: 2880 blocks
    float4 x;
    unsigned short* dh;
    unsigned short* dl;
    int di;
    if (i < 442368) {
        x  = (i < 393216) ? ((const float4*)bert)[i] : ((const float4*)query)[i - 393216];
        dh = Ahi; dl = Alo; di = i;
    } else {
        x  = ((const float4*)Ww)[i - 442368];
        dh = Whi; dl = Wlo; di = i - 442368;
    }
    ushort4 h, l;
    h.x = f_to_bf16_rne(x.x); l.x = f_to_bf16_rne(x.x - bf16_to_f(h.x));
    h.y = f_to_bf16_rne(x.y); l.y = f_to_bf16_rne(x.y - bf16_to_f(h.y));
    h.z = f_to_bf16_rne(x.z); l.z = f_to_bf16_rne(x.z - bf16_to_f(h.z));
    h.w = f_to_bf16_rne(x.w); l.w = f_to_bf16_rne(x.w - bf16_to_f(h.w));
    ((ushort4*)dh)[di] = h;
    ((ushort4*)dl)[di] = l;
}

// ---- split-bf16 MFMA gemm: C[m][n] = sum_k A[m][k]*W'[n][k]  (+ W_b[n] for m>=2048)
// A: Acat [2304][768] bf16 hi/lo (bert rows 0..2047, query rows 2048..2303)
// W: Wcat [1536][768] bf16 hi/lo; row for output-col n is (2n + sel), sel=0 bert / 1 query.
// Per verified gfx950 16x16x32 layout: A lane l: [l&15][(l>>4)*8+j]; B lane l: [(l>>4)*8+j][l&15];
// D lane l reg r: row=(l>>4)*4+r, col=l&15.
// block = 256 thr = 4 waves; wave tile 32(M)x64(N); block tile 128x64; grid (768/64, 2304/128).
__global__ __launch_bounds__(256) void gemm_mfma_split(
    const unsigned short* __restrict__ Ahi, const unsigned short* __restrict__ Alo,
    const unsigned short* __restrict__ Whi, const unsigned short* __restrict__ Wlo,
    const float* __restrict__ Wb, float* __restrict__ C)
{
    const int t  = threadIdx.x;
    const int wv = t >> 6;
    const int l  = t & 63;
    const int lr = l & 15;          // row-in-fragment
    const int kg = l >> 4;          // k-group (0..3) -> k offset kg*8
    const int n0 = blockIdx.x * 64;
    const int bm0 = blockIdx.y * 128;
    const int m0 = bm0 + wv * 32;
    const bool isq = (bm0 >= 2048);
    const int wsel = isq ? 1 : 0;

    const size_t aoff = (size_t)(m0 + lr) * 768 + kg * 8;
    const unsigned short* pAh = Ahi + aoff;
    const unsigned short* pAl = Alo + aoff;
    const size_t boff = (size_t)(2 * (n0 + lr) + wsel) * 768 + kg * 8;
    const unsigned short* pBh = Whi + boff;
    const unsigned short* pBl = Wlo + boff;

    f32x4 acc[2][4];
    #pragma unroll
    for (int i = 0; i < 2; ++i)
        #pragma unroll
        for (int j = 0; j < 4; ++j) acc[i][j] = (f32x4){0.f, 0.f, 0.f, 0.f};

    #pragma unroll 2
    for (int k0 = 0; k0 < 768; k0 += 32) {
        bf16x8 ah[2], al[2], bh[4], bl[4];
        #pragma unroll
        for (int i = 0; i < 2; ++i) {
            ah[i] = *(const bf16x8*)(pAh + (size_t)i * 16 * 768 + k0);
            al[i] = *(const bf16x8*)(pAl + (size_t)i * 16 * 768 + k0);
        }
        #pragma unroll
        for (int j = 0; j < 4; ++j) {
            bh[j] = *(const bf16x8*)(pBh + (size_t)j * 32 * 768 + k0);
            bl[j] = *(const bf16x8*)(pBl + (size_t)j * 32 * 768 + k0);
        }
        #pragma unroll
        for (int i = 0; i < 2; ++i)
            #pragma unroll
            for (int j = 0; j < 4; ++j) {
                acc[i][j] = __builtin_amdgcn_mfma_f32_16x16x32_bf16(ah[i], bh[j], acc[i][j], 0, 0, 0);
                acc[i][j] = __builtin_amdgcn_mfma_f32_16x16x32_bf16(ah[i], bl[j], acc[i][j], 0, 0, 0);
                acc[i][j] = __builtin_amdgcn_mfma_f32_16x16x32_bf16(al[i], bh[j], acc[i][j], 0, 0, 0);
            }
    }

    #pragma unroll
    for (int j = 0; j < 4; ++j) {
        const int col = n0 + j * 16 + lr;
        const float bias = isq ? Wb[col] : 0.f;
        #pragma unroll
        for (int i = 0; i < 2; ++i)
            #pragma unroll
            for (int r = 0; r < 4; ++r) {
                const int row = m0 + i * 16 + kg * 4 + r;
                C[(size_t)row * 768 + col] = acc[i][j][r] + bias;
            }
    }
}

// x[b,q,l] = sum_k tanh(bp[b,l,k] + qpb[b,q,k]) * v_w[k]  + v_b
__global__ __launch_bounds__(256) void attn_scores(
    const float* __restrict__ bp, const float* __restrict__ qpb,
    const float* __restrict__ v_w, const float* __restrict__ v_b,
    float* __restrict__ X)
{
    __shared__ __align__(16) float bpL[16][68];
    __shared__ __align__(16) float qpL[16][68];
    __shared__ __align__(16) float vwL[64];
    const int t   = threadIdx.x;
    const int b   = blockIdx.z;
    const int q0  = blockIdx.y * 16;
    const int l0  = blockIdx.x * 16;
    const int li  = t & 15;
    const int qi  = t >> 4;
    const int row = t >> 4;
    const int col = (t & 15) << 2;
    const float* bprow = bp  + (size_t)(b * 512 + l0 + row) * 768;
    const float* qprow = qpb + (size_t)(b * 64  + q0 + row) * 768;
    float acc = 0.f;

    for (int k0 = 0; k0 < 768; k0 += 64) {
        *(float4*)&bpL[row][col] = *(const float4*)(bprow + k0 + col);
        *(float4*)&qpL[row][col] = *(const float4*)(qprow + k0 + col);
        if (t < 16) *(float4*)&vwL[t << 2] = *(const float4*)(v_w + k0 + (t << 2));
        __syncthreads();
        #pragma unroll
        for (int kk = 0; kk < 64; kk += 4) {
            float4 b4 = *(const float4*)&bpL[li][kk];
            float4 q4 = *(const float4*)&qpL[qi][kk];
            float4 v4 = *(const float4*)&vwL[kk];
            acc = fmaf(tanh_fast(b4.x + q4.x), v4.x, acc);
            acc = fmaf(tanh_fast(b4.y + q4.y), v4.y, acc);
            acc = fmaf(tanh_fast(b4.z + q4.z), v4.z, acc);
            acc = fmaf(tanh_fast(b4.w + q4.w), v4.w, acc);
        }
        __syncthreads();
    }
    X[(size_t)(b * 64 + q0 + qi) * 512 + l0 + li] = acc + v_b[0];
}

// masked softmax over l (512) per (b,q) row
__global__ __launch_bounds__(512) void softmax_mask(
    const float* __restrict__ X, const int* __restrict__ mask,
    float* __restrict__ out)
{
    const int bq  = blockIdx.x;
    const int b   = bq >> 6;
    const int l   = threadIdx.x;
    const int wid = l >> 6;
    __shared__ float red[8];

    float v = X[(size_t)bq * 512 + l];
    const bool mk = (mask[b * 512 + l] != 0);
    v = mk ? v : -1e25f;

    float m = v;
    #pragma unroll
    for (int o = 32; o; o >>= 1) m = fmaxf(m, __shfl_xor(m, o));
    if ((l & 63) == 0) red[wid] = m;
    __syncthreads();
    #pragma unroll
    for (int i = 0; i < 8; ++i) m = fmaxf(m, red[i]);

    float e = __builtin_amdgcn_exp2f((v - m) * LOG2E);
    float s = e;
    #pragma unroll
    for (int o = 32; o; o >>= 1) s += __shfl_xor(s, o);
    __syncthreads();
    if ((l & 63) == 0) red[wid] = s;
    __syncthreads();
    s = 0.f;
    #pragma unroll
    for (int i = 0; i < 8; ++i) s += red[i];

    out[(size_t)bq * 512 + l] = e / s;
}

extern "C" void kernel_launch(void* const* d_in, const int* in_sizes, int n_in,
                              void* d_out, int out_size, void* d_ws, size_t ws_size,
                              hipStream_t stream)
{
    const float* bert  = (const float*)d_in[0];   // (4,512,768) f32
    const float* query = (const float*)d_in[1];   // (4,64,768)  f32
    const int*   mask  = (const int*)  d_in[2];   // (4,512)     int32 (bool)
    const float* W_w   = (const float*)d_in[3];   // (768,1536)  f32
    const float* W_b   = (const float*)d_in[4];   // (768,)      f32
    const float* v_w   = (const float*)d_in[5];   // (1,768)     f32
    const float* v_b   = (const float*)d_in[6];   // (1,)        f32

    // workspace carve
    float* C = (float*)d_ws;                       // [2304][768] f32  (bp rows 0..2047, qp+bias rows 2048..)
    float* X = C + (size_t)2304 * 768;             // [256][512] f32
    unsigned short* Ahi = (unsigned short*)(X + (size_t)256 * 512);
    unsigned short* Alo = Ahi + (size_t)2304 * 768;
    unsigned short* Whi = Alo + (size_t)2304 * 768;
    unsigned short* Wlo = Whi + (size_t)1536 * 768;
    float* out = (float*)d_out;                    // (4,64,512) f32

    // 1. split-cast bert|query -> Acat, W_w -> Wcat   (737280 float4 -> 2880 blocks)
    cast_split_all<<<2880, 256, 0, stream>>>(bert, query, W_w, Ahi, Alo, Whi, Wlo);
    // 2. fused MFMA gemm: C = [bert;query] . W'^T (+bias on query rows)
    gemm_mfma_split<<<dim3(12, 18), 256, 0, stream>>>(Ahi, Alo, Whi, Wlo, W_b, C);
    // 3. x = sum_k tanh(bp + qpb) * v_w + v_b
    attn_scores<<<dim3(32, 4, 4), 256, 0, stream>>>(C, C + (size_t)2048 * 768, v_w, v_b, X);
    // 4. masked softmax
    softmax_mask<<<dim3(256), 512, 0, stream>>>(X, mask, out);
}

// Round 3
// 147.644 us; speedup vs baseline: 1.2970x; 1.0047x over previous
//
#include <hip/hip_runtime.h>
#include <hip/hip_bf16.h>

#define LOG2E    1.4426950408889634f
#define TWOLOG2E 2.8853900817779268f

typedef short bf16x8 __attribute__((ext_vector_type(8)));
typedef float f32x4  __attribute__((ext_vector_type(4)));
typedef unsigned short u16x8 __attribute__((ext_vector_type(8)));

static __device__ __forceinline__ float bf16_to_f(unsigned short u) {
    union { unsigned int i; float f; } v; v.i = ((unsigned int)u) << 16; return v.f;
}
static __device__ __forceinline__ unsigned short f_to_bf16_rne(float x) {
    union { float f; unsigned int i; } v; v.f = x;
    unsigned int lsb = (v.i >> 16) & 1u;
    v.i += 0x7fffu + lsb;
    return (unsigned short)(v.i >> 16);
}

// ---------------------------------------------------------------------------
// cast_frag: f32 inputs -> split bf16 hi/lo, stored in MFMA-fragment-linear
// layout so GEMM operand loads are 1KB coalesced wave loads.
//   A (rows = [bert(2048) | query(256)], k=768):
//     Afrag[((mt*24 + kt)*64 + lane)*8 + e] = A[mt*16 + (lane&15)][kt*32 + (lane>>4)*8 + e]
//   W ("rows" = output col n per sel, k=768), scaled by TWOLOG2E:
//     Wfrag[(((sel*48+nt)*24 + kt)*64 + lane)*8 + e]
//         = W_w[(nt*16+(lane&15))*1536 + sel*768 + kt*32 + (lane>>4)*8 + e] * TWOLOG2E
// A entries: 144*24*64 = 221184.  W entries: 96*24*64 = 147456.  total 368640.
// ---------------------------------------------------------------------------
__global__ __launch_bounds__(256) void cast_frag(
    const float* __restrict__ bert, const float* __restrict__ query,
    const float* __restrict__ Ww,
    unsigned short* __restrict__ Ahf, unsigned short* __restrict__ Alf,
    unsigned short* __restrict__ Whf, unsigned short* __restrict__ Wlf)
{
    const int i    = blockIdx.x * 256 + threadIdx.x;   // exact grid: 1440*256
    const int lane = i & 63;
    const float* src;
    float scale;
    unsigned short *dh, *dl;
    size_t di;
    if (i < 221184) {
        const int rest = i >> 6;
        const int kt = rest % 24, mt = rest / 24;
        const int m  = mt * 16 + (lane & 15);
        src = ((m < 2048) ? bert + (size_t)m * 768
                          : query + (size_t)(m - 2048) * 768)
              + kt * 32 + (lane >> 4) * 8;
        scale = 1.0f;
        dh = Ahf; dl = Alf; di = (size_t)i * 8;
    } else {
        const int j = i - 221184;
        const int rest = j >> 6;
        const int kt = rest % 24, nt2 = rest / 24;     // nt2 = sel*48 + nt
        const int sel = nt2 >> 6 ? 1 : (nt2 >= 48);    // sel = nt2/48 (0 or 1)
        const int n   = (nt2 - sel * 48) * 16 + (lane & 15);
        src = Ww + (size_t)n * 1536 + sel * 768 + kt * 32 + (lane >> 4) * 8;
        scale = TWOLOG2E;
        dh = Whf; dl = Wlf; di = (size_t)j * 8;
    }
    float4 x0 = *(const float4*)src;
    float4 x1 = *(const float4*)(src + 4);
    float xs[8] = {x0.x * scale, x0.y * scale, x0.z * scale, x0.w * scale,
                   x1.x * scale, x1.y * scale, x1.z * scale, x1.w * scale};
    u16x8 h, l;
    #pragma unroll
    for (int e = 0; e < 8; ++e) {
        unsigned short hh = f_to_bf16_rne(xs[e]);
        h[e] = hh;
        l[e] = f_to_bf16_rne(xs[e] - bf16_to_f(hh));
    }
    *(u16x8*)(dh + di) = h;
    *(u16x8*)(dl + di) = l;
}

// ---------------------------------------------------------------------------
// gemm_frag: split-bf16 3-pass MFMA, operands in fragment-linear layout.
// 1 wave per block, wave tile 32(m) x 32(n), grid = 72*24 = 1728 waves.
// C[m][n] = sum_k A[m][k]*W'[n][k]  (+ TWOLOG2E*W_b[n] on query rows m>=2048)
// ---------------------------------------------------------------------------
__global__ __launch_bounds__(64) void gemm_frag(
    const unsigned short* __restrict__ Ahf, const unsigned short* __restrict__ Alf,
    const unsigned short* __restrict__ Whf, const unsigned short* __restrict__ Wlf,
    const float* __restrict__ Wb, float* __restrict__ C)
{
    const int l    = threadIdx.x;            // 0..63
    const int w    = blockIdx.x;             // 0..1727
    const int mt_w = w / 24;                 // 0..71
    const int nt_w = w % 24;                 // 0..23
    const int m0   = mt_w * 32;
    const int n0   = nt_w * 32;
    const bool isq = (m0 >= 2048);
    const int  fmt = mt_w * 2;               // A frag tile (16-row) index
    const int  fnt = (isq ? 48 : 0) + nt_w * 2;  // W frag tile index
    const int  lr  = l & 15;
    const int  kg  = l >> 4;

    // per-frag-tile stride: 24 ktiles * 64 lanes * 8 elem = 12288 shorts
    const unsigned short* pAh = Ahf + (size_t)fmt * 12288 + l * 8;
    const unsigned short* pAl = Alf + (size_t)fmt * 12288 + l * 8;
    const unsigned short* pBh = Whf + (size_t)fnt * 12288 + l * 8;
    const unsigned short* pBl = Wlf + (size_t)fnt * 12288 + l * 8;

    f32x4 acc[2][2];
    #pragma unroll
    for (int i = 0; i < 2; ++i)
        #pragma unroll
        for (int j = 0; j < 2; ++j) acc[i][j] = (f32x4){0.f, 0.f, 0.f, 0.f};

    #pragma unroll 4
    for (int kt = 0; kt < 24; ++kt) {
        bf16x8 ah[2], al[2], bh[2], bl[2];
        #pragma unroll
        for (int i = 0; i < 2; ++i) {
            ah[i] = *(const bf16x8*)(pAh + (size_t)i * 12288 + kt * 512);
            al[i] = *(const bf16x8*)(pAl + (size_t)i * 12288 + kt * 512);
            bh[i] = *(const bf16x8*)(pBh + (size_t)i * 12288 + kt * 512);
            bl[i] = *(const bf16x8*)(pBl + (size_t)i * 12288 + kt * 512);
        }
        #pragma unroll
        for (int i = 0; i < 2; ++i)
            #pragma unroll
            for (int j = 0; j < 2; ++j) {
                acc[i][j] = __builtin_amdgcn_mfma_f32_16x16x32_bf16(ah[i], bh[j], acc[i][j], 0, 0, 0);
                acc[i][j] = __builtin_amdgcn_mfma_f32_16x16x32_bf16(ah[i], bl[j], acc[i][j], 0, 0, 0);
                acc[i][j] = __builtin_amdgcn_mfma_f32_16x16x32_bf16(al[i], bh[j], acc[i][j], 0, 0, 0);
            }
    }

    #pragma unroll
    for (int j = 0; j < 2; ++j) {
        const int col  = n0 + j * 16 + lr;
        const float bias = isq ? Wb[col] * TWOLOG2E : 0.f;
        #pragma unroll
        for (int i = 0; i < 2; ++i)
            #pragma unroll
            for (int r = 0; r < 4; ++r) {
                const int row = m0 + i * 16 + kg * 4 + r;
                C[(size_t)row * 768 + col] = acc[i][j][r] + bias;
            }
    }
}

// ---------------------------------------------------------------------------
// attn_scores: X[b,q,l] = -2 * sum_k v_w[k] * rcp(1 + exp2(bp[l,k] + qp[q,k]))
// (args pre-scaled by 2*log2(e) in the GEMM; Vsum & v_b dropped: softmax is
//  shift-invariant per row). No LDS: C is L2-resident (7 MB).
// ---------------------------------------------------------------------------
__global__ __launch_bounds__(256) void attn_scores(
    const float* __restrict__ C, const float* __restrict__ v_w,
    float* __restrict__ X)
{
    const int t  = threadIdx.x;
    const int b  = blockIdx.z;
    const int q  = blockIdx.y * 16 + (t >> 4);
    const int lx = blockIdx.x * 16 + (t & 15);
    const float* pb = C + (size_t)(b * 512 + lx) * 768;
    const float* pq = C + (size_t)(2048 + b * 64 + q) * 768;
    float acc = 0.f;
    #pragma unroll 4
    for (int k = 0; k < 768; k += 4) {
        float4 bv = *(const float4*)(pb + k);
        float4 qv = *(const float4*)(pq + k);
        float4 vv = *(const float4*)(v_w + k);   // wave-uniform -> s_load
        acc = fmaf(vv.x, __builtin_amdgcn_rcpf(1.0f + __builtin_amdgcn_exp2f(bv.x + qv.x)), acc);
        acc = fmaf(vv.y, __builtin_amdgcn_rcpf(1.0f + __builtin_amdgcn_exp2f(bv.y + qv.y)), acc);
        acc = fmaf(vv.z, __builtin_amdgcn_rcpf(1.0f + __builtin_amdgcn_exp2f(bv.z + qv.z)), acc);
        acc = fmaf(vv.w, __builtin_amdgcn_rcpf(1.0f + __builtin_amdgcn_exp2f(bv.w + qv.w)), acc);
    }
    X[(size_t)(b * 64 + q) * 512 + lx] = -2.f * acc;
}

// masked softmax over l (512) per (b,q) row
__global__ __launch_bounds__(512) void softmax_mask(
    const float* __restrict__ X, const int* __restrict__ mask,
    float* __restrict__ out)
{
    const int bq  = blockIdx.x;
    const int b   = bq >> 6;
    const int l   = threadIdx.x;
    const int wid = l >> 6;
    __shared__ float red[8];

    float v = X[(size_t)bq * 512 + l];
    const bool mk = (mask[b * 512 + l] != 0);
    v = mk ? v : -1e25f;

    float m = v;
    #pragma unroll
    for (int o = 32; o; o >>= 1) m = fmaxf(m, __shfl_xor(m, o));
    if ((l & 63) == 0) red[wid] = m;
    __syncthreads();
    #pragma unroll
    for (int i = 0; i < 8; ++i) m = fmaxf(m, red[i]);

    float e = __builtin_amdgcn_exp2f((v - m) * LOG2E);
    float s = e;
    #pragma unroll
    for (int o = 32; o; o >>= 1) s += __shfl_xor(s, o);
    __syncthreads();
    if ((l & 63) == 0) red[wid] = s;
    __syncthreads();
    s = 0.f;
    #pragma unroll
    for (int i = 0; i < 8; ++i) s += red[i];

    out[(size_t)bq * 512 + l] = e / s;
}

extern "C" void kernel_launch(void* const* d_in, const int* in_sizes, int n_in,
                              void* d_out, int out_size, void* d_ws, size_t ws_size,
                              hipStream_t stream)
{
    const float* bert  = (const float*)d_in[0];   // (4,512,768) f32
    const float* query = (const float*)d_in[1];   // (4,64,768)  f32
    const int*   mask  = (const int*)  d_in[2];   // (4,512)     int32 (bool)
    const float* W_w   = (const float*)d_in[3];   // (768,1536)  f32
    const float* W_b   = (const float*)d_in[4];   // (768,)      f32
    const float* v_w   = (const float*)d_in[5];   // (1,768)     f32
    const float* v_b   = (const float*)d_in[6];   // (1,)  (unused: softmax shift-invariant)
    (void)v_b;

    float* C = (float*)d_ws;                       // [2304][768] f32 (bp | qp+bias), 7.08 MB
    float* X = C + (size_t)2304 * 768;             // [256][512] f32
    unsigned short* Ahf = (unsigned short*)(X + (size_t)256 * 512);
    unsigned short* Alf = Ahf + (size_t)2304 * 768;
    unsigned short* Whf = Alf + (size_t)2304 * 768;
    unsigned short* Wlf = Whf + (size_t)1536 * 768;
    float* out = (float*)d_out;                    // (4,64,512) f32

    cast_frag<<<1440, 256, 0, stream>>>(bert, query, W_w, Ahf, Alf, Whf, Wlf);
    gemm_frag<<<1728, 64, 0, stream>>>(Ahf, Alf, Whf, Wlf, W_b, C);
    attn_scores<<<dim3(32, 4, 4), 256, 0, stream>>>(C, v_w, X);
    softmax_mask<<<dim3(256), 512, 0, stream>>>(X, mask, out);
}